// Round 4
// baseline (141.110 us; speedup 1.0000x reference)
//
#include <hip/hip_runtime.h>
#include <hip/hip_bf16.h>
#include <math.h>

#define BN 32
#define NN 2048
#define KK 32
#define DD 16
#define SC 16   // split copies of s to shorten atomic chains

// ws layout (floats):
// 0      : accN    [1024]
// 1024   : accSx   [16384]
// 17408  : accSxx  [16384]
// 33792  : s       [SC*16384 = 262144]   (zero block ends at 295936)
// 295936 : mu      [16384]
// 312320 : invsig  [16384]
// 328704 : cc      [1024]
// 329728 : R       [BN*NN*KK = 2097152]

// MODE 0: accumulate N, Sx, Sxx.  MODE 1: write R.
// FIRST 1: mu comes from mu0 (sigma=1, pi=1/32).
template <int MODE, int FIRST>
__global__ __launch_bounds__(256, 2) void k_estep(
    const float* __restrict__ x, const float* __restrict__ mu,
    const float* __restrict__ invsig, const float* __restrict__ cc,
    float* __restrict__ accN, float* __restrict__ accSx,
    float* __restrict__ accSxx, float* __restrict__ Rout) {
    const int b = blockIdx.x >> 4;      // 32 b
    const int chunk = blockIdx.x & 15;  // 16 chunks of 128 n
    const int tid = threadIdx.x;
    const int wave = tid >> 6;
    const int lane = tid & 63;
    const int k = lane & 31;
    const int jj = lane >> 5;

    // per-lane cluster params in registers
    float mk[DD], ik[DD];
    {
        const float4* mp = (const float4*)(mu + (size_t)(b * KK + k) * DD);
#pragma unroll
        for (int q = 0; q < 4; q++) {
            float4 m4 = mp[q];
            mk[q*4+0]=m4.x; mk[q*4+1]=m4.y; mk[q*4+2]=m4.z; mk[q*4+3]=m4.w;
        }
        if (FIRST) {
#pragma unroll
            for (int d = 0; d < DD; d++) ik[d] = 1.0f;
        } else {
            const float4* ip = (const float4*)(invsig + (size_t)(b * KK + k) * DD);
#pragma unroll
            for (int q = 0; q < 4; q++) {
                float4 i4 = ip[q];
                ik[q*4+0]=i4.x; ik[q*4+1]=i4.y; ik[q*4+2]=i4.z; ik[q*4+3]=i4.w;
            }
        }
    }
    const float ck = FIRST ? -3.4657359028f : cc[b * KK + k];

    float aN = 0.f, aSx[DD], aSxx[DD];
#pragma unroll
    for (int d = 0; d < DD; d++) { aSx[d] = 0.f; aSxx[d] = 0.f; }

#pragma unroll 2
    for (int i = 0; i < 16; i++) {
        const int n = chunk * 128 + i * 8 + wave * 2 + jj;
        const float4* xp = (const float4*)(x + ((size_t)b * NN + n) * DD);
        float xv[DD];
#pragma unroll
        for (int q = 0; q < 4; q++) {
            float4 v = xp[q];
            xv[q*4+0]=v.x; xv[q*4+1]=v.y; xv[q*4+2]=v.z; xv[q*4+3]=v.w;
        }
        float qd = 0.f;
#pragma unroll
        for (int d = 0; d < DD; d++) {
            float z = (xv[d] - mk[d]) * ik[d];
            qd = fmaf(z, z, qd);
        }
        float logit = ck - 0.5f * qd;
        // softmax over k = 32 lanes of the half-wave
        float m = logit;
#pragma unroll
        for (int off = 1; off < 32; off <<= 1) m = fmaxf(m, __shfl_xor(m, off));
        float e = __expf(logit - m);
        float ssum = e;
#pragma unroll
        for (int off = 1; off < 32; off <<= 1) ssum += __shfl_xor(ssum, off);
        float g = e / ssum;

        if (MODE == 1) {
            Rout[((size_t)b * NN + n) * KK + k] = g;
        } else {
            aN += g;
#pragma unroll
            for (int d = 0; d < DD; d++) {
                aSx[d] = fmaf(g, xv[d], aSx[d]);
                aSxx[d] = fmaf(g * xv[d], xv[d], aSxx[d]);
            }
        }
    }

    if (MODE == 0) {
        __shared__ float red[4][KK * 33];
        aN += __shfl_xor(aN, 32);
#pragma unroll
        for (int d = 0; d < DD; d++) {
            aSx[d] += __shfl_xor(aSx[d], 32);
            aSxx[d] += __shfl_xor(aSxx[d], 32);
        }
        if (jj == 0) {
            red[wave][k * 33 + 0] = aN;
#pragma unroll
            for (int d = 0; d < DD; d++) {
                red[wave][k * 33 + 1 + d] = aSx[d];
                red[wave][k * 33 + 17 + d] = aSxx[d];
            }
        }
        __syncthreads();
        for (int idx = tid; idx < KK * 33; idx += 256) {
            float v = red[0][idx] + red[1][idx] + red[2][idx] + red[3][idx];
            int kk2 = idx / 33, j = idx % 33;
            float* dst;
            if (j == 0) dst = accN + b * KK + kk2;
            else if (j < 17) dst = accSx + (size_t)(b * KK + kk2) * DD + (j - 1);
            else dst = accSxx + (size_t)(b * KK + kk2) * DD + (j - 17);
            unsafeAtomicAdd(dst, v);
        }
    }
}

__global__ void k_finalize(float* __restrict__ accN, float* __restrict__ accSx,
                           float* __restrict__ accSxx, float* __restrict__ mu,
                           float* __restrict__ invsig, float* __restrict__ cc) {
    int i = blockIdx.x * 256 + threadIdx.x;  // (b,k)
    if (i >= BN * KK) return;
    float N = accN[i];
    accN[i] = 0.f;
    float invN = 1.0f / N;
    float sumlog = 0.f;
#pragma unroll
    for (int d = 0; d < DD; d++) {
        float m_ = accSx[(size_t)i * DD + d] * invN;
        float v = accSxx[(size_t)i * DD + d] * invN - m_ * m_;
        v = fmaxf(v, 1e-12f);
        mu[(size_t)i * DD + d] = m_;
        invsig[(size_t)i * DD + d] = rsqrtf(v);
        sumlog += 0.5f * logf(v);  // log(sigma)
        accSx[(size_t)i * DD + d] = 0.f;
        accSxx[(size_t)i * DD + d] = 0.f;
    }
    cc[i] = logf(N * (1.0f / NN)) - sumlog;
}

// v3: thread = one (k,d) slot; lanes own consecutive slots so W reads are
// per-lane 64B rows (dense 4KB per wave per j). x rows are block-uniform ->
// scalar loads (SGPR), no LDS anywhere, 32 static accumulators (no spill).
__global__ __launch_bounds__(512, 4) void k_caps(
    const float* __restrict__ x, const float* __restrict__ W,
    const float* __restrict__ R, float* __restrict__ s) {
    const int tid = threadIdx.x;           // slot = k*16 + d
    const int k = tid >> 4;
    const int n0 = blockIdx.x * 4;
    float* sc = s + (size_t)(blockIdx.x & (SC - 1)) * (BN * KK * DD);

    float sacc[BN];
#pragma unroll
    for (int b = 0; b < BN; b++) sacc[b] = 0.f;

#pragma unroll
    for (int j = 0; j < 4; j++) {
        // W row for this slot: 64B, per-lane (dense across the wave)
        const float4* wp = (const float4*)(W + (((size_t)(n0 + j) * KK * DD) + tid) * DD);
        float4 w0 = wp[0], w1 = wp[1], w2 = wp[2], w3 = wp[3];
        const float* xj = x + (size_t)(n0 + j) * DD;
        const float* Rj = R + (size_t)(n0 + j) * KK + k;
#pragma unroll 4
        for (int b = 0; b < BN; b++) {
            const float4* xb = (const float4*)(xj + (size_t)b * (NN * DD));
            float4 xa = xb[0], xc = xb[1], xe = xb[2], xg = xb[3];
            float p0 = w0.x * xa.x, p1 = w0.y * xa.y, p2 = w0.z * xa.z, p3 = w0.w * xa.w;
            p0 = fmaf(w1.x, xc.x, p0); p1 = fmaf(w1.y, xc.y, p1);
            p2 = fmaf(w1.z, xc.z, p2); p3 = fmaf(w1.w, xc.w, p3);
            p0 = fmaf(w2.x, xe.x, p0); p1 = fmaf(w2.y, xe.y, p1);
            p2 = fmaf(w2.z, xe.z, p2); p3 = fmaf(w2.w, xe.w, p3);
            p0 = fmaf(w3.x, xg.x, p0); p1 = fmaf(w3.y, xg.y, p1);
            p2 = fmaf(w3.z, xg.z, p2); p3 = fmaf(w3.w, xg.w, p3);
            float caps = (p0 + p1) + (p2 + p3);
            float r = Rj[(size_t)b * (NN * KK)];
            sacc[b] = fmaf(r, caps, sacc[b]);
        }
    }
#pragma unroll
    for (int b = 0; b < BN; b++) {
        unsafeAtomicAdd(sc + (size_t)b * (KK * DD) + tid, sacc[b]);
    }
}

__global__ void k_squash(const float* __restrict__ s, float* __restrict__ out) {
    int i = blockIdx.x * 256 + threadIdx.x;  // (b,k)
    if (i >= BN * KK) return;
    float4 v0 = make_float4(0,0,0,0), v1 = v0, v2 = v0, v3 = v0;
#pragma unroll
    for (int c = 0; c < SC; c++) {
        const float4* sp = (const float4*)(s + (size_t)c * (BN * KK * DD) + (size_t)i * DD);
        float4 a = sp[0], b = sp[1], cc2 = sp[2], dd2 = sp[3];
        v0.x+=a.x; v0.y+=a.y; v0.z+=a.z; v0.w+=a.w;
        v1.x+=b.x; v1.y+=b.y; v1.z+=b.z; v1.w+=b.w;
        v2.x+=cc2.x; v2.y+=cc2.y; v2.z+=cc2.z; v2.w+=cc2.w;
        v3.x+=dd2.x; v3.y+=dd2.y; v3.z+=dd2.z; v3.w+=dd2.w;
    }
    float ss = 1e-7f;
    ss += v0.x*v0.x + v0.y*v0.y + v0.z*v0.z + v0.w*v0.w;
    ss += v1.x*v1.x + v1.y*v1.y + v1.z*v1.z + v1.w*v1.w;
    ss += v2.x*v2.x + v2.y*v2.y + v2.z*v2.z + v2.w*v2.w;
    ss += v3.x*v3.x + v3.y*v3.y + v3.z*v3.z + v3.w*v3.w;
    float sc = sqrtf(ss) / (1.0f + ss);
    float4* op = (float4*)(out + (size_t)i * DD);
    v0.x*=sc; v0.y*=sc; v0.z*=sc; v0.w*=sc;
    v1.x*=sc; v1.y*=sc; v1.z*=sc; v1.w*=sc;
    v2.x*=sc; v2.y*=sc; v2.z*=sc; v2.w*=sc;
    v3.x*=sc; v3.y*=sc; v3.z*=sc; v3.w*=sc;
    op[0]=v0; op[1]=v1; op[2]=v2; op[3]=v3;
}

extern "C" void kernel_launch(void* const* d_in, const int* in_sizes, int n_in,
                              void* d_out, int out_size, void* d_ws, size_t ws_size,
                              hipStream_t stream) {
    const float* x   = (const float*)d_in[0];
    const float* W   = (const float*)d_in[1];
    const float* mu0 = (const float*)d_in[2];
    float* ws      = (float*)d_ws;
    float* accN    = ws;
    float* accSx   = ws + 1024;
    float* accSxx  = ws + 17408;
    float* s       = ws + 33792;
    float* mu      = ws + 295936;
    float* invsig  = ws + 312320;
    float* cc      = ws + 328704;
    float* R       = ws + 329728;

    hipMemsetAsync(ws, 0, (size_t)295936 * sizeof(float), stream);

    // iteration 1 (mu = mu0, sigma = 1, pi = 1/32)
    k_estep<0, 1><<<512, 256, 0, stream>>>(x, mu0, nullptr, nullptr, accN, accSx, accSxx, nullptr);
    k_finalize<<<4, 256, 0, stream>>>(accN, accSx, accSxx, mu, invsig, cc);
    // iteration 2
    k_estep<0, 0><<<512, 256, 0, stream>>>(x, mu, invsig, cc, accN, accSx, accSxx, nullptr);
    k_finalize<<<4, 256, 0, stream>>>(accN, accSx, accSxx, mu, invsig, cc);
    // iteration 3: only R is needed downstream
    k_estep<1, 0><<<512, 256, 0, stream>>>(x, mu, invsig, cc, nullptr, nullptr, nullptr, R);

    k_caps<<<512, 512, 0, stream>>>(x, W, R, s);
    k_squash<<<4, 256, 0, stream>>>(s, (float*)d_out);
}

// Round 5
// 130.666 us; speedup vs baseline: 1.0799x; 1.0799x over previous
//
#include <hip/hip_runtime.h>
#include <hip/hip_bf16.h>
#include <math.h>

#define BN 32
#define NN 2048
#define KK 32
#define DD 16
#define SC 32   // split copies of s to shorten atomic chains

// ws layout (floats):
// 0      : accN    [1024]
// 1024   : accSx   [16384]
// 17408  : accSxx  [16384]
// 33792  : s       [SC*16384 = 524288]   (zero block ends at 558080)
// 558080 : mu      [16384]
// 574464 : invsig  [16384]
// 590848 : cc      [1024]
// 591872 : R       [BN*NN*KK = 2097152]

// MODE 0: accumulate N, Sx, Sxx.  MODE 1: write R.
// FIRST 1: mu comes from mu0 (sigma=1, pi=1/32).
template <int MODE, int FIRST>
__global__ __launch_bounds__(256, 2) void k_estep(
    const float* __restrict__ x, const float* __restrict__ mu,
    const float* __restrict__ invsig, const float* __restrict__ cc,
    float* __restrict__ accN, float* __restrict__ accSx,
    float* __restrict__ accSxx, float* __restrict__ Rout) {
    const int b = blockIdx.x >> 4;      // 32 b
    const int chunk = blockIdx.x & 15;  // 16 chunks of 128 n
    const int tid = threadIdx.x;
    const int wave = tid >> 6;
    const int lane = tid & 63;
    const int k = lane & 31;
    const int jj = lane >> 5;

    // per-lane cluster params in registers
    float mk[DD], ik[DD];
    {
        const float4* mp = (const float4*)(mu + (size_t)(b * KK + k) * DD);
#pragma unroll
        for (int q = 0; q < 4; q++) {
            float4 m4 = mp[q];
            mk[q*4+0]=m4.x; mk[q*4+1]=m4.y; mk[q*4+2]=m4.z; mk[q*4+3]=m4.w;
        }
        if (FIRST) {
#pragma unroll
            for (int d = 0; d < DD; d++) ik[d] = 1.0f;
        } else {
            const float4* ip = (const float4*)(invsig + (size_t)(b * KK + k) * DD);
#pragma unroll
            for (int q = 0; q < 4; q++) {
                float4 i4 = ip[q];
                ik[q*4+0]=i4.x; ik[q*4+1]=i4.y; ik[q*4+2]=i4.z; ik[q*4+3]=i4.w;
            }
        }
    }
    const float ck = FIRST ? -3.4657359028f : cc[b * KK + k];

    float aN = 0.f, aSx[DD], aSxx[DD];
#pragma unroll
    for (int d = 0; d < DD; d++) { aSx[d] = 0.f; aSxx[d] = 0.f; }

#pragma unroll 2
    for (int i = 0; i < 16; i++) {
        const int n = chunk * 128 + i * 8 + wave * 2 + jj;
        const float4* xp = (const float4*)(x + ((size_t)b * NN + n) * DD);
        float xv[DD];
#pragma unroll
        for (int q = 0; q < 4; q++) {
            float4 v = xp[q];
            xv[q*4+0]=v.x; xv[q*4+1]=v.y; xv[q*4+2]=v.z; xv[q*4+3]=v.w;
        }
        float qd = 0.f;
#pragma unroll
        for (int d = 0; d < DD; d++) {
            float z = (xv[d] - mk[d]) * ik[d];
            qd = fmaf(z, z, qd);
        }
        float logit = ck - 0.5f * qd;
        // softmax over k = 32 lanes of the half-wave
        float m = logit;
#pragma unroll
        for (int off = 1; off < 32; off <<= 1) m = fmaxf(m, __shfl_xor(m, off));
        float e = __expf(logit - m);
        float ssum = e;
#pragma unroll
        for (int off = 1; off < 32; off <<= 1) ssum += __shfl_xor(ssum, off);
        float g = e / ssum;

        if (MODE == 1) {
            Rout[((size_t)b * NN + n) * KK + k] = g;
        } else {
            aN += g;
#pragma unroll
            for (int d = 0; d < DD; d++) {
                aSx[d] = fmaf(g, xv[d], aSx[d]);
                aSxx[d] = fmaf(g * xv[d], xv[d], aSxx[d]);
            }
        }
    }

    if (MODE == 0) {
        __shared__ float red[4][KK * 33];
        aN += __shfl_xor(aN, 32);
#pragma unroll
        for (int d = 0; d < DD; d++) {
            aSx[d] += __shfl_xor(aSx[d], 32);
            aSxx[d] += __shfl_xor(aSxx[d], 32);
        }
        if (jj == 0) {
            red[wave][k * 33 + 0] = aN;
#pragma unroll
            for (int d = 0; d < DD; d++) {
                red[wave][k * 33 + 1 + d] = aSx[d];
                red[wave][k * 33 + 17 + d] = aSxx[d];
            }
        }
        __syncthreads();
        for (int idx = tid; idx < KK * 33; idx += 256) {
            float v = red[0][idx] + red[1][idx] + red[2][idx] + red[3][idx];
            int kk2 = idx / 33, j = idx % 33;
            float* dst;
            if (j == 0) dst = accN + b * KK + kk2;
            else if (j < 17) dst = accSx + (size_t)(b * KK + kk2) * DD + (j - 1);
            else dst = accSxx + (size_t)(b * KK + kk2) * DD + (j - 17);
            unsafeAtomicAdd(dst, v);
        }
    }
}

__global__ void k_finalize(float* __restrict__ accN, float* __restrict__ accSx,
                           float* __restrict__ accSxx, float* __restrict__ mu,
                           float* __restrict__ invsig, float* __restrict__ cc) {
    int i = blockIdx.x * 256 + threadIdx.x;  // (b,k)
    if (i >= BN * KK) return;
    float N = accN[i];
    accN[i] = 0.f;
    float invN = 1.0f / N;
    float sumlog = 0.f;
#pragma unroll
    for (int d = 0; d < DD; d++) {
        float m_ = accSx[(size_t)i * DD + d] * invN;
        float v = accSxx[(size_t)i * DD + d] * invN - m_ * m_;
        v = fmaxf(v, 1e-12f);
        mu[(size_t)i * DD + d] = m_;
        invsig[(size_t)i * DD + d] = rsqrtf(v);
        sumlog += 0.5f * logf(v);  // log(sigma)
        accSx[(size_t)i * DD + d] = 0.f;
        accSxx[(size_t)i * DD + d] = 0.f;
    }
    cc[i] = logf(N * (1.0f / NN)) - sumlog;
}

// v4: thread = one (k,d) slot (512 threads); W reads per-lane 64B rows.
// x rows are block-uniform -> compiler scalarizes to s_load (verified R4:
// SGPR=48). b-loop FULLY unrolled so sacc[32] is statically indexed and
// stays in VGPRs (R4 regression: partial unroll -> scratch, VGPR=36).
__global__ __launch_bounds__(512, 4) void k_caps(
    const float* __restrict__ x, const float* __restrict__ W,
    const float* __restrict__ R, float* __restrict__ s) {
    const int tid = threadIdx.x;           // slot = k*16 + d
    const int k = tid >> 4;
    const int n0 = blockIdx.x * 4;
    float* sc = s + (size_t)(blockIdx.x & (SC - 1)) * (BN * KK * DD);

    float sacc[BN];
#pragma unroll
    for (int b = 0; b < BN; b++) sacc[b] = 0.f;

    for (int j = 0; j < 4; j++) {
        // W row for this slot: 64B, per-lane (dense across the wave)
        const float4* wp = (const float4*)(W + (((size_t)(n0 + j) * KK * DD) + tid) * DD);
        float4 w0 = wp[0], w1 = wp[1], w2 = wp[2], w3 = wp[3];
        const float* xj = x + (size_t)(n0 + j) * DD;
        const float* Rj = R + (size_t)(n0 + j) * KK + k;
#pragma unroll
        for (int b = 0; b < BN; b++) {
            const float4* xb = (const float4*)(xj + (size_t)b * (NN * DD));
            float4 xa = xb[0], xc = xb[1], xe = xb[2], xg = xb[3];
            float p0 = w0.x * xa.x, p1 = w0.y * xa.y, p2 = w0.z * xa.z, p3 = w0.w * xa.w;
            p0 = fmaf(w1.x, xc.x, p0); p1 = fmaf(w1.y, xc.y, p1);
            p2 = fmaf(w1.z, xc.z, p2); p3 = fmaf(w1.w, xc.w, p3);
            p0 = fmaf(w2.x, xe.x, p0); p1 = fmaf(w2.y, xe.y, p1);
            p2 = fmaf(w2.z, xe.z, p2); p3 = fmaf(w2.w, xe.w, p3);
            p0 = fmaf(w3.x, xg.x, p0); p1 = fmaf(w3.y, xg.y, p1);
            p2 = fmaf(w3.z, xg.z, p2); p3 = fmaf(w3.w, xg.w, p3);
            float caps = (p0 + p1) + (p2 + p3);
            float r = Rj[(size_t)b * (NN * KK)];
            sacc[b] = fmaf(r, caps, sacc[b]);
        }
    }
#pragma unroll
    for (int b = 0; b < BN; b++) {
        unsafeAtomicAdd(sc + (size_t)b * (KK * DD) + tid, sacc[b]);
    }
}

__global__ void k_squash(const float* __restrict__ s, float* __restrict__ out) {
    int i = blockIdx.x * 256 + threadIdx.x;  // (b,k)
    if (i >= BN * KK) return;
    float4 v0 = make_float4(0,0,0,0), v1 = v0, v2 = v0, v3 = v0;
#pragma unroll
    for (int c = 0; c < SC; c++) {
        const float4* sp = (const float4*)(s + (size_t)c * (BN * KK * DD) + (size_t)i * DD);
        float4 a = sp[0], b = sp[1], cc2 = sp[2], dd2 = sp[3];
        v0.x+=a.x; v0.y+=a.y; v0.z+=a.z; v0.w+=a.w;
        v1.x+=b.x; v1.y+=b.y; v1.z+=b.z; v1.w+=b.w;
        v2.x+=cc2.x; v2.y+=cc2.y; v2.z+=cc2.z; v2.w+=cc2.w;
        v3.x+=dd2.x; v3.y+=dd2.y; v3.z+=dd2.z; v3.w+=dd2.w;
    }
    float ss = 1e-7f;
    ss += v0.x*v0.x + v0.y*v0.y + v0.z*v0.z + v0.w*v0.w;
    ss += v1.x*v1.x + v1.y*v1.y + v1.z*v1.z + v1.w*v1.w;
    ss += v2.x*v2.x + v2.y*v2.y + v2.z*v2.z + v2.w*v2.w;
    ss += v3.x*v3.x + v3.y*v3.y + v3.z*v3.z + v3.w*v3.w;
    float sc = sqrtf(ss) / (1.0f + ss);
    float4* op = (float4*)(out + (size_t)i * DD);
    v0.x*=sc; v0.y*=sc; v0.z*=sc; v0.w*=sc;
    v1.x*=sc; v1.y*=sc; v1.z*=sc; v1.w*=sc;
    v2.x*=sc; v2.y*=sc; v2.z*=sc; v2.w*=sc;
    v3.x*=sc; v3.y*=sc; v3.z*=sc; v3.w*=sc;
    op[0]=v0; op[1]=v1; op[2]=v2; op[3]=v3;
}

extern "C" void kernel_launch(void* const* d_in, const int* in_sizes, int n_in,
                              void* d_out, int out_size, void* d_ws, size_t ws_size,
                              hipStream_t stream) {
    const float* x   = (const float*)d_in[0];
    const float* W   = (const float*)d_in[1];
    const float* mu0 = (const float*)d_in[2];
    float* ws      = (float*)d_ws;
    float* accN    = ws;
    float* accSx   = ws + 1024;
    float* accSxx  = ws + 17408;
    float* s       = ws + 33792;
    float* mu      = ws + 558080;
    float* invsig  = ws + 574464;
    float* cc      = ws + 590848;
    float* R       = ws + 591872;

    hipMemsetAsync(ws, 0, (size_t)558080 * sizeof(float), stream);

    // iteration 1 (mu = mu0, sigma = 1, pi = 1/32)
    k_estep<0, 1><<<512, 256, 0, stream>>>(x, mu0, nullptr, nullptr, accN, accSx, accSxx, nullptr);
    k_finalize<<<4, 256, 0, stream>>>(accN, accSx, accSxx, mu, invsig, cc);
    // iteration 2
    k_estep<0, 0><<<512, 256, 0, stream>>>(x, mu, invsig, cc, accN, accSx, accSxx, nullptr);
    k_finalize<<<4, 256, 0, stream>>>(accN, accSx, accSxx, mu, invsig, cc);
    // iteration 3: only R is needed downstream
    k_estep<1, 0><<<512, 256, 0, stream>>>(x, mu, invsig, cc, nullptr, nullptr, nullptr, R);

    k_caps<<<512, 512, 0, stream>>>(x, W, R, s);
    k_squash<<<4, 256, 0, stream>>>(s, (float*)d_out);
}

// Round 6
// 129.469 us; speedup vs baseline: 1.0899x; 1.0092x over previous
//
#include <hip/hip_runtime.h>
#include <hip/hip_bf16.h>
#include <math.h>

#define BN 32
#define NN 2048
#define KK 32
#define DD 16
#define SC 32   // split copies of s to shorten atomic chains

// ws layout (floats):
// 0      : accN_A  [1024]
// 1024   : accSx_A [16384]
// 17408  : accSxx_A[16384]
// 33792  : accN_B  [1024]
// 34816  : accSx_B [16384]
// 51200  : accSxx_B[16384]
// 67584  : s       [SC*16384 = 524288]   (zero block ends at 591872)
// 591872 : R       [BN*NN*KK = 2097152]

// MODE 0: accumulate N, Sx, Sxx into out*.  MODE 1: write R.
// FIRST 1: params from mu0 (sigma=1, pi=1/32); else inline-finalize from in*.
template <int MODE, int FIRST>
__global__ __launch_bounds__(256, 4) void k_estep(
    const float* __restrict__ x, const float* __restrict__ mu0,
    const float* __restrict__ inN, const float* __restrict__ inSx,
    const float* __restrict__ inSxx, float* __restrict__ outN,
    float* __restrict__ outSx, float* __restrict__ outSxx,
    float* __restrict__ Rout) {
    const int b = blockIdx.x >> 5;      // 32 b
    const int chunk = blockIdx.x & 31;  // 32 chunks of 64 n
    const int tid = threadIdx.x;
    const int wave = tid >> 6;
    const int lane = tid & 63;
    const int k = lane & 31;
    const int jj = lane >> 5;

    float mk[DD], ik[DD], ck;
    if (FIRST) {
        const float4* mp = (const float4*)(mu0 + (size_t)(b * KK + k) * DD);
#pragma unroll
        for (int q = 0; q < 4; q++) {
            float4 m4 = mp[q];
            mk[q*4+0]=m4.x; mk[q*4+1]=m4.y; mk[q*4+2]=m4.z; mk[q*4+3]=m4.w;
        }
#pragma unroll
        for (int d = 0; d < DD; d++) ik[d] = 1.0f;
        ck = -3.4657359028f;  // log(1/32)
    } else {
        // inline finalize: recompute this (b,k)'s stats from accumulators
        float N = inN[b * KK + k];
        float invN = 1.0f / N;
        float sxv[DD], sxxv[DD];
        const float4* sxp  = (const float4*)(inSx  + (size_t)(b * KK + k) * DD);
        const float4* sxxp = (const float4*)(inSxx + (size_t)(b * KK + k) * DD);
#pragma unroll
        for (int q = 0; q < 4; q++) {
            float4 a = sxp[q], c = sxxp[q];
            sxv[q*4+0]=a.x; sxv[q*4+1]=a.y; sxv[q*4+2]=a.z; sxv[q*4+3]=a.w;
            sxxv[q*4+0]=c.x; sxxv[q*4+1]=c.y; sxxv[q*4+2]=c.z; sxxv[q*4+3]=c.w;
        }
        float sumlog = 0.f;
#pragma unroll
        for (int d = 0; d < DD; d++) {
            float m_ = sxv[d] * invN;
            float v = fmaxf(sxxv[d] * invN - m_ * m_, 1e-12f);
            mk[d] = m_;
            ik[d] = rsqrtf(v);
            sumlog += __logf(v);
        }
        ck = __logf(N * (1.0f / NN)) - 0.5f * sumlog;
    }

    float aN = 0.f, aSx[DD], aSxx[DD];
#pragma unroll
    for (int d = 0; d < DD; d++) { aSx[d] = 0.f; aSxx[d] = 0.f; }

#pragma unroll 2
    for (int i = 0; i < 8; i++) {
        const int n = chunk * 64 + i * 8 + wave * 2 + jj;
        const float4* xp = (const float4*)(x + ((size_t)b * NN + n) * DD);
        float xv[DD];
#pragma unroll
        for (int q = 0; q < 4; q++) {
            float4 v = xp[q];
            xv[q*4+0]=v.x; xv[q*4+1]=v.y; xv[q*4+2]=v.z; xv[q*4+3]=v.w;
        }
        float qd = 0.f;
#pragma unroll
        for (int d = 0; d < DD; d++) {
            float z = (xv[d] - mk[d]) * ik[d];
            qd = fmaf(z, z, qd);
        }
        float logit = ck - 0.5f * qd;
        // softmax over k = 32 lanes of the half-wave
        float m = logit;
#pragma unroll
        for (int off = 1; off < 32; off <<= 1) m = fmaxf(m, __shfl_xor(m, off));
        float e = __expf(logit - m);
        float ssum = e;
#pragma unroll
        for (int off = 1; off < 32; off <<= 1) ssum += __shfl_xor(ssum, off);
        float g = e / ssum;

        if (MODE == 1) {
            Rout[((size_t)b * NN + n) * KK + k] = g;
        } else {
            aN += g;
#pragma unroll
            for (int d = 0; d < DD; d++) {
                aSx[d] = fmaf(g, xv[d], aSx[d]);
                aSxx[d] = fmaf(g * xv[d], xv[d], aSxx[d]);
            }
        }
    }

    if (MODE == 0) {
        __shared__ float red[4][KK * 33];
        aN += __shfl_xor(aN, 32);
#pragma unroll
        for (int d = 0; d < DD; d++) {
            aSx[d] += __shfl_xor(aSx[d], 32);
            aSxx[d] += __shfl_xor(aSxx[d], 32);
        }
        if (jj == 0) {
            red[wave][k * 33 + 0] = aN;
#pragma unroll
            for (int d = 0; d < DD; d++) {
                red[wave][k * 33 + 1 + d] = aSx[d];
                red[wave][k * 33 + 17 + d] = aSxx[d];
            }
        }
        __syncthreads();
        for (int idx = tid; idx < KK * 33; idx += 256) {
            float v = red[0][idx] + red[1][idx] + red[2][idx] + red[3][idx];
            int kk2 = idx / 33, j = idx % 33;
            float* dst;
            if (j == 0) dst = outN + b * KK + kk2;
            else if (j < 17) dst = outSx + (size_t)(b * KK + kk2) * DD + (j - 1);
            else dst = outSxx + (size_t)(b * KK + kk2) * DD + (j - 17);
            unsafeAtomicAdd(dst, v);
        }
    }
}

// v5: thread = one (k,d) slot (512 threads); W reads per-lane 64B rows.
// x rows are block-uniform -> scalar s_loads (verified R4/R5 SGPR counts).
// b-sweep split into two sequential 16-b halves (#pragma unroll 1 firewall)
// so peak live regs ~= 16 sacc + 16 W + addr ~= 40 -- matching what the
// allocator actually grants (R3/R4/R5 all spilled with bigger working sets).
__global__ __launch_bounds__(512, 4) void k_caps(
    const float* __restrict__ x, const float* __restrict__ W,
    const float* __restrict__ R, float* __restrict__ s) {
    const int tid = threadIdx.x;           // slot = k*16 + d
    const int k = tid >> 4;
    const int n0 = blockIdx.x * 4;
    float* sc = s + (size_t)(blockIdx.x & (SC - 1)) * (BN * KK * DD);

#pragma unroll 1
    for (int half = 0; half < 2; half++) {
        float sacc[16];
#pragma unroll
        for (int i = 0; i < 16; i++) sacc[i] = 0.f;

#pragma unroll 1
        for (int j = 0; j < 4; j++) {
            const float4* wp = (const float4*)(W + (((size_t)(n0 + j) * (KK * DD)) + tid) * DD);
            float4 w0 = wp[0], w1 = wp[1], w2 = wp[2], w3 = wp[3];
            const float* xj = x + (size_t)(n0 + j) * DD + (size_t)half * (16 * NN * DD);
            const float* Rj = R + (size_t)(n0 + j) * KK + k + (size_t)half * (16 * NN * KK);
#pragma unroll
            for (int i = 0; i < 16; i++) {
                const float4* xb = (const float4*)(xj + (size_t)i * (NN * DD));
                float4 xa = xb[0], xc = xb[1], xe = xb[2], xg = xb[3];
                float p0 = w0.x * xa.x, p1 = w0.y * xa.y, p2 = w0.z * xa.z, p3 = w0.w * xa.w;
                p0 = fmaf(w1.x, xc.x, p0); p1 = fmaf(w1.y, xc.y, p1);
                p2 = fmaf(w1.z, xc.z, p2); p3 = fmaf(w1.w, xc.w, p3);
                p0 = fmaf(w2.x, xe.x, p0); p1 = fmaf(w2.y, xe.y, p1);
                p2 = fmaf(w2.z, xe.z, p2); p3 = fmaf(w2.w, xe.w, p3);
                p0 = fmaf(w3.x, xg.x, p0); p1 = fmaf(w3.y, xg.y, p1);
                p2 = fmaf(w3.z, xg.z, p2); p3 = fmaf(w3.w, xg.w, p3);
                float caps = (p0 + p1) + (p2 + p3);
                float r = Rj[(size_t)i * (NN * KK)];
                sacc[i] = fmaf(r, caps, sacc[i]);
            }
        }
        const int boff = half * 16;
#pragma unroll
        for (int i = 0; i < 16; i++) {
            unsafeAtomicAdd(sc + (size_t)(boff + i) * (KK * DD) + tid, sacc[i]);
        }
    }
}

__global__ void k_squash(const float* __restrict__ s, float* __restrict__ out) {
    int i = blockIdx.x * 256 + threadIdx.x;  // (b,k)
    if (i >= BN * KK) return;
    float4 v0 = make_float4(0,0,0,0), v1 = v0, v2 = v0, v3 = v0;
#pragma unroll
    for (int c = 0; c < SC; c++) {
        const float4* sp = (const float4*)(s + (size_t)c * (BN * KK * DD) + (size_t)i * DD);
        float4 a = sp[0], b = sp[1], cc2 = sp[2], dd2 = sp[3];
        v0.x+=a.x; v0.y+=a.y; v0.z+=a.z; v0.w+=a.w;
        v1.x+=b.x; v1.y+=b.y; v1.z+=b.z; v1.w+=b.w;
        v2.x+=cc2.x; v2.y+=cc2.y; v2.z+=cc2.z; v2.w+=cc2.w;
        v3.x+=dd2.x; v3.y+=dd2.y; v3.z+=dd2.z; v3.w+=dd2.w;
    }
    float ss = 1e-7f;
    ss += v0.x*v0.x + v0.y*v0.y + v0.z*v0.z + v0.w*v0.w;
    ss += v1.x*v1.x + v1.y*v1.y + v1.z*v1.z + v1.w*v1.w;
    ss += v2.x*v2.x + v2.y*v2.y + v2.z*v2.z + v2.w*v2.w;
    ss += v3.x*v3.x + v3.y*v3.y + v3.z*v3.z + v3.w*v3.w;
    float sc = sqrtf(ss) / (1.0f + ss);
    float4* op = (float4*)(out + (size_t)i * DD);
    v0.x*=sc; v0.y*=sc; v0.z*=sc; v0.w*=sc;
    v1.x*=sc; v1.y*=sc; v1.z*=sc; v1.w*=sc;
    v2.x*=sc; v2.y*=sc; v2.z*=sc; v2.w*=sc;
    v3.x*=sc; v3.y*=sc; v3.z*=sc; v3.w*=sc;
    op[0]=v0; op[1]=v1; op[2]=v2; op[3]=v3;
}

extern "C" void kernel_launch(void* const* d_in, const int* in_sizes, int n_in,
                              void* d_out, int out_size, void* d_ws, size_t ws_size,
                              hipStream_t stream) {
    const float* x   = (const float*)d_in[0];
    const float* W   = (const float*)d_in[1];
    const float* mu0 = (const float*)d_in[2];
    float* ws      = (float*)d_ws;
    float* aN_A    = ws;
    float* aSx_A   = ws + 1024;
    float* aSxx_A  = ws + 17408;
    float* aN_B    = ws + 33792;
    float* aSx_B   = ws + 34816;
    float* aSxx_B  = ws + 51200;
    float* s       = ws + 67584;
    float* R       = ws + 591872;

    hipMemsetAsync(ws, 0, (size_t)591872 * sizeof(float), stream);

    // iteration 1 (mu = mu0, sigma = 1, pi = 1/32) -> acc A
    k_estep<0, 1><<<1024, 256, 0, stream>>>(x, mu0, nullptr, nullptr, nullptr,
                                            aN_A, aSx_A, aSxx_A, nullptr);
    // iteration 2: stats from A (inline finalize) -> acc B
    k_estep<0, 0><<<1024, 256, 0, stream>>>(x, nullptr, aN_A, aSx_A, aSxx_A,
                                            aN_B, aSx_B, aSxx_B, nullptr);
    // iteration 3: stats from B -> R only
    k_estep<1, 0><<<1024, 256, 0, stream>>>(x, nullptr, aN_B, aSx_B, aSxx_B,
                                            nullptr, nullptr, nullptr, R);

    k_caps<<<512, 512, 0, stream>>>(x, W, R, s);
    k_squash<<<4, 256, 0, stream>>>(s, (float*)d_out);
}

// Round 7
// 113.511 us; speedup vs baseline: 1.2431x; 1.1406x over previous
//
#include <hip/hip_runtime.h>
#include <hip/hip_bf16.h>
#include <math.h>

#define BN 32
#define NN 2048
#define KK 32
#define DD 16
#define SC 64        // split copies of s (atomic chain = 512/64 = 8)
#define ACC_C 4      // split copies of estep accumulators (chain = 32/4 = 8)
#define ACC_STRIDE 33792  // per-copy: N[1024] + Sx[16384] + Sxx[16384]

// ws layout (floats):
// 0        : accA   [ACC_C*33792 = 135168]
// 135168   : accB   [135168]                (zero block: 0..1318912)
// 270336   : s      [SC*16384 = 1048576]
// 1318912  : R      [BN*NN*KK = 2097152]
// total 3416064 floats = 13.7 MB

// MODE 0: accumulate N, Sx, Sxx into accOut (copy = chunk&3). MODE 1: write R.
// FIRST 1: params from mu0 (sigma=1, pi=1/32); else inline-finalize from accIn.
template <int MODE, int FIRST>
__global__ __launch_bounds__(256, 4) void k_estep(
    const float* __restrict__ x, const float* __restrict__ mu0,
    const float* __restrict__ accIn, float* __restrict__ accOut,
    float* __restrict__ Rout) {
    const int b = blockIdx.x >> 5;      // 32 b
    const int chunk = blockIdx.x & 31;  // 32 chunks of 64 n
    const int tid = threadIdx.x;
    const int wave = tid >> 6;
    const int lane = tid & 63;
    const int k = lane & 31;
    const int jj = lane >> 5;

    float mk[DD], ik[DD], ck;
    if (FIRST) {
        const float4* mp = (const float4*)(mu0 + (size_t)(b * KK + k) * DD);
#pragma unroll
        for (int q = 0; q < 4; q++) {
            float4 m4 = mp[q];
            mk[q*4+0]=m4.x; mk[q*4+1]=m4.y; mk[q*4+2]=m4.z; mk[q*4+3]=m4.w;
        }
#pragma unroll
        for (int d = 0; d < DD; d++) ik[d] = 1.0f;
        ck = -3.4657359028f;  // log(1/32)
    } else {
        float N = 0.f, sxv[DD], sxxv[DD];
#pragma unroll
        for (int d = 0; d < DD; d++) { sxv[d] = 0.f; sxxv[d] = 0.f; }
#pragma unroll
        for (int c = 0; c < ACC_C; c++) {
            const float* base = accIn + (size_t)c * ACC_STRIDE;
            N += base[b * KK + k];
            const float4* sxp  = (const float4*)(base + 1024  + (size_t)(b * KK + k) * DD);
            const float4* sxxp = (const float4*)(base + 17408 + (size_t)(b * KK + k) * DD);
#pragma unroll
            for (int q = 0; q < 4; q++) {
                float4 a = sxp[q], c2 = sxxp[q];
                sxv[q*4+0]+=a.x; sxv[q*4+1]+=a.y; sxv[q*4+2]+=a.z; sxv[q*4+3]+=a.w;
                sxxv[q*4+0]+=c2.x; sxxv[q*4+1]+=c2.y; sxxv[q*4+2]+=c2.z; sxxv[q*4+3]+=c2.w;
            }
        }
        float invN = 1.0f / N;
        float sumlog = 0.f;
#pragma unroll
        for (int d = 0; d < DD; d++) {
            float m_ = sxv[d] * invN;
            float v = fmaxf(sxxv[d] * invN - m_ * m_, 1e-12f);
            mk[d] = m_;
            ik[d] = rsqrtf(v);
            sumlog += __logf(v);
        }
        ck = __logf(N * (1.0f / NN)) - 0.5f * sumlog;
    }

    float aN = 0.f, aSx[DD], aSxx[DD];
#pragma unroll
    for (int d = 0; d < DD; d++) { aSx[d] = 0.f; aSxx[d] = 0.f; }

#pragma unroll 2
    for (int i = 0; i < 8; i++) {
        const int n = chunk * 64 + i * 8 + wave * 2 + jj;
        const float4* xp = (const float4*)(x + ((size_t)b * NN + n) * DD);
        float xv[DD];
#pragma unroll
        for (int q = 0; q < 4; q++) {
            float4 v = xp[q];
            xv[q*4+0]=v.x; xv[q*4+1]=v.y; xv[q*4+2]=v.z; xv[q*4+3]=v.w;
        }
        float qd = 0.f;
#pragma unroll
        for (int d = 0; d < DD; d++) {
            float z = (xv[d] - mk[d]) * ik[d];
            qd = fmaf(z, z, qd);
        }
        float logit = ck - 0.5f * qd;
        float m = logit;
#pragma unroll
        for (int off = 1; off < 32; off <<= 1) m = fmaxf(m, __shfl_xor(m, off));
        float e = __expf(logit - m);
        float ssum = e;
#pragma unroll
        for (int off = 1; off < 32; off <<= 1) ssum += __shfl_xor(ssum, off);
        float g = e / ssum;

        if (MODE == 1) {
            Rout[((size_t)b * NN + n) * KK + k] = g;
        } else {
            aN += g;
#pragma unroll
            for (int d = 0; d < DD; d++) {
                aSx[d] = fmaf(g, xv[d], aSx[d]);
                aSxx[d] = fmaf(g * xv[d], xv[d], aSxx[d]);
            }
        }
    }

    if (MODE == 0) {
        __shared__ float red[4][KK * 33];
        aN += __shfl_xor(aN, 32);
#pragma unroll
        for (int d = 0; d < DD; d++) {
            aSx[d] += __shfl_xor(aSx[d], 32);
            aSxx[d] += __shfl_xor(aSxx[d], 32);
        }
        if (jj == 0) {
            red[wave][k * 33 + 0] = aN;
#pragma unroll
            for (int d = 0; d < DD; d++) {
                red[wave][k * 33 + 1 + d] = aSx[d];
                red[wave][k * 33 + 17 + d] = aSxx[d];
            }
        }
        __syncthreads();
        float* outc = accOut + (size_t)(chunk & (ACC_C - 1)) * ACC_STRIDE;
        for (int idx = tid; idx < KK * 33; idx += 256) {
            float v = red[0][idx] + red[1][idx] + red[2][idx] + red[3][idx];
            int kk2 = idx / 33, j = idx % 33;
            float* dst;
            if (j == 0) dst = outc + b * KK + kk2;
            else if (j < 17) dst = outc + 1024 + (size_t)(b * KK + kk2) * DD + (j - 1);
            else dst = outc + 17408 + (size_t)(b * KK + kk2) * DD + (j - 17);
            unsafeAtomicAdd(dst, v);
        }
    }
}

// v6: thread = (k,d) slot; x+R staged in LDS (uniform-broadcast reads, free
// per bank rules); W per-lane 64B rows with explicit register double-buffer
// across the fully-unrolled j-loop (prefetch j+1 while computing j).
// b-sweep in two 16-wide halves so sacc stays 16 regs (R5 lesson), but W
// re-read in half 2 is cache-served (R6 FETCH evidence).
__global__ __launch_bounds__(512, 2) void k_caps(
    const float* __restrict__ x, const float* __restrict__ W,
    const float* __restrict__ R, float* __restrict__ s) {
    __shared__ float xs[4][BN][DD];  // 8 KB
    __shared__ float rs[4][BN][KK];  // 16 KB
    const int tid = threadIdx.x;     // slot = k*16 + d
    const int k = tid >> 4;
    const int n0 = blockIdx.x * 4;
    float* sc = s + (size_t)(blockIdx.x & (SC - 1)) * (BN * KK * DD);

    {   // x: 4n*32b*4 = 512 float4, one per thread
        int j = tid >> 7, b = (tid >> 2) & 31, e4 = tid & 3;
        *(float4*)&xs[j][b][e4 * 4] =
            *(const float4*)(x + ((size_t)b * NN + n0 + j) * DD + e4 * 4);
    }
#pragma unroll
    for (int q = tid; q < 1024; q += 512) {  // R: 1024 float4, two per thread
        int j = q >> 8, b = (q >> 3) & 31, k4 = q & 7;
        *(float4*)&rs[j][b][k4 * 4] =
            *(const float4*)(R + ((size_t)b * NN + n0 + j) * KK + k4 * 4);
    }
    __syncthreads();

#pragma unroll 1
    for (int half = 0; half < 2; half++) {
        float sacc[16];
#pragma unroll
        for (int i = 0; i < 16; i++) sacc[i] = 0.f;

        const float4* wp0 = (const float4*)(W + ((size_t)n0 * (KK * DD) + tid) * DD);
        float4 wa0 = wp0[0], wa1 = wp0[1], wa2 = wp0[2], wa3 = wp0[3];

#pragma unroll
        for (int j = 0; j < 4; j++) {
            float4 wb0, wb1, wb2, wb3;
            if (j < 3) {
                const float4* wp = (const float4*)(W + ((size_t)(n0 + j + 1) * (KK * DD) + tid) * DD);
                wb0 = wp[0]; wb1 = wp[1]; wb2 = wp[2]; wb3 = wp[3];
            } else {
                wb0 = wa0; wb1 = wa1; wb2 = wa2; wb3 = wa3;
            }
#pragma unroll
            for (int i = 0; i < 16; i++) {
                const int b = half * 16 + i;
                const float4* xv = (const float4*)&xs[j][b][0];
                float4 xa = xv[0], xc = xv[1], xe = xv[2], xg = xv[3];
                float r = rs[j][b][k];
                float p0 = wa0.x * xa.x, p1 = wa0.y * xa.y;
                float p2 = wa0.z * xa.z, p3 = wa0.w * xa.w;
                p0 = fmaf(wa1.x, xc.x, p0); p1 = fmaf(wa1.y, xc.y, p1);
                p2 = fmaf(wa1.z, xc.z, p2); p3 = fmaf(wa1.w, xc.w, p3);
                p0 = fmaf(wa2.x, xe.x, p0); p1 = fmaf(wa2.y, xe.y, p1);
                p2 = fmaf(wa2.z, xe.z, p2); p3 = fmaf(wa2.w, xe.w, p3);
                p0 = fmaf(wa3.x, xg.x, p0); p1 = fmaf(wa3.y, xg.y, p1);
                p2 = fmaf(wa3.z, xg.z, p2); p3 = fmaf(wa3.w, xg.w, p3);
                float caps = (p0 + p1) + (p2 + p3);
                sacc[i] = fmaf(r, caps, sacc[i]);
            }
            wa0 = wb0; wa1 = wb1; wa2 = wb2; wa3 = wb3;
        }
#pragma unroll
        for (int i = 0; i < 16; i++) {
            unsafeAtomicAdd(sc + (size_t)(half * 16 + i) * (KK * DD) + tid, sacc[i]);
        }
    }
}

// thread per (b,k,d); sum SC copies coalesced; 16-lane shuffle for the norm.
__global__ void k_squash(const float* __restrict__ s, float* __restrict__ out) {
    int idx = blockIdx.x * 256 + threadIdx.x;  // 16384 = BN*KK*DD
    float v = 0.f;
#pragma unroll 8
    for (int c = 0; c < SC; c++) v += s[(size_t)c * (BN * KK * DD) + idx];
    float ss = v * v;
#pragma unroll
    for (int off = 1; off < 16; off <<= 1) ss += __shfl_xor(ss, off);
    ss += 1e-7f;
    float scale = sqrtf(ss) / (1.0f + ss);
    out[idx] = v * scale;
}

extern "C" void kernel_launch(void* const* d_in, const int* in_sizes, int n_in,
                              void* d_out, int out_size, void* d_ws, size_t ws_size,
                              hipStream_t stream) {
    const float* x   = (const float*)d_in[0];
    const float* W   = (const float*)d_in[1];
    const float* mu0 = (const float*)d_in[2];
    float* ws   = (float*)d_ws;
    float* accA = ws;
    float* accB = ws + 135168;
    float* s    = ws + 270336;
    float* R    = ws + 1318912;

    hipMemsetAsync(ws, 0, (size_t)1318912 * sizeof(float), stream);

    // iteration 1 (mu = mu0, sigma = 1, pi = 1/32) -> accA
    k_estep<0, 1><<<1024, 256, 0, stream>>>(x, mu0, nullptr, accA, nullptr);
    // iteration 2: finalize from accA inline -> accB
    k_estep<0, 0><<<1024, 256, 0, stream>>>(x, nullptr, accA, accB, nullptr);
    // iteration 3: finalize from accB inline -> R only
    k_estep<1, 0><<<1024, 256, 0, stream>>>(x, nullptr, accB, nullptr, R);

    k_caps<<<512, 512, 0, stream>>>(x, W, R, s);
    k_squash<<<64, 256, 0, stream>>>(s, (float*)d_out);
}

// Round 8
// 108.035 us; speedup vs baseline: 1.3062x; 1.0507x over previous
//
#include <hip/hip_runtime.h>
#include <hip/hip_bf16.h>
#include <math.h>

#define BN 32
#define NN 2048
#define KK 32
#define DD 16
#define SC 64        // split copies of s (atomic chain = 512/64 = 8)
#define ACC_C 4      // split copies of estep accumulators (chain = 32/4 = 8)
#define ACC_STRIDE 33792  // per-copy: N[1024] + Sx[16384] + Sxx[16384]

// ws layout (floats):
// 0        : accA   [ACC_C*33792 = 135168]
// 135168   : accB   [135168]                (zero block: 0..1318912)
// 270336   : s      [SC*16384 = 1048576]
// 1318912  : R      [BN*NN*KK = 2097152]

// MODE 0: accumulate N, Sx, Sxx into accOut (copy = chunk&3). MODE 1: write R.
// FIRST 1: params from mu0 (sigma=1, pi=1/32); else inline-finalize from accIn.
template <int MODE, int FIRST>
__global__ __launch_bounds__(256, 4) void k_estep(
    const float* __restrict__ x, const float* __restrict__ mu0,
    const float* __restrict__ accIn, float* __restrict__ accOut,
    float* __restrict__ Rout) {
    const int b = blockIdx.x >> 5;      // 32 b
    const int chunk = blockIdx.x & 31;  // 32 chunks of 64 n
    const int tid = threadIdx.x;
    const int wave = tid >> 6;
    const int lane = tid & 63;
    const int k = lane & 31;
    const int jj = lane >> 5;

    float mk[DD], ik[DD], ck;
    if (FIRST) {
        const float4* mp = (const float4*)(mu0 + (size_t)(b * KK + k) * DD);
#pragma unroll
        for (int q = 0; q < 4; q++) {
            float4 m4 = mp[q];
            mk[q*4+0]=m4.x; mk[q*4+1]=m4.y; mk[q*4+2]=m4.z; mk[q*4+3]=m4.w;
        }
#pragma unroll
        for (int d = 0; d < DD; d++) ik[d] = 1.0f;
        ck = -3.4657359028f;  // log(1/32)
    } else {
        float N = 0.f, sxv[DD], sxxv[DD];
#pragma unroll
        for (int d = 0; d < DD; d++) { sxv[d] = 0.f; sxxv[d] = 0.f; }
#pragma unroll
        for (int c = 0; c < ACC_C; c++) {
            const float* base = accIn + (size_t)c * ACC_STRIDE;
            N += base[b * KK + k];
            const float4* sxp  = (const float4*)(base + 1024  + (size_t)(b * KK + k) * DD);
            const float4* sxxp = (const float4*)(base + 17408 + (size_t)(b * KK + k) * DD);
#pragma unroll
            for (int q = 0; q < 4; q++) {
                float4 a = sxp[q], c2 = sxxp[q];
                sxv[q*4+0]+=a.x; sxv[q*4+1]+=a.y; sxv[q*4+2]+=a.z; sxv[q*4+3]+=a.w;
                sxxv[q*4+0]+=c2.x; sxxv[q*4+1]+=c2.y; sxxv[q*4+2]+=c2.z; sxxv[q*4+3]+=c2.w;
            }
        }
        float invN = 1.0f / N;
        float sumlog = 0.f;
#pragma unroll
        for (int d = 0; d < DD; d++) {
            float m_ = sxv[d] * invN;
            float v = fmaxf(sxxv[d] * invN - m_ * m_, 1e-12f);
            mk[d] = m_;
            ik[d] = rsqrtf(v);
            sumlog += __logf(v);
        }
        ck = __logf(N * (1.0f / NN)) - 0.5f * sumlog;
    }

    float aN = 0.f, aSx[DD], aSxx[DD];
#pragma unroll
    for (int d = 0; d < DD; d++) { aSx[d] = 0.f; aSxx[d] = 0.f; }

#pragma unroll 4
    for (int i = 0; i < 8; i++) {
        const int n = chunk * 64 + i * 8 + wave * 2 + jj;
        const float4* xp = (const float4*)(x + ((size_t)b * NN + n) * DD);
        float xv[DD];
#pragma unroll
        for (int q = 0; q < 4; q++) {
            float4 v = xp[q];
            xv[q*4+0]=v.x; xv[q*4+1]=v.y; xv[q*4+2]=v.z; xv[q*4+3]=v.w;
        }
        float qd = 0.f;
#pragma unroll
        for (int d = 0; d < DD; d++) {
            float z = (xv[d] - mk[d]) * ik[d];
            qd = fmaf(z, z, qd);
        }
        float logit = ck - 0.5f * qd;
        float m = logit;
#pragma unroll
        for (int off = 1; off < 32; off <<= 1) m = fmaxf(m, __shfl_xor(m, off));
        float e = __expf(logit - m);
        float ssum = e;
#pragma unroll
        for (int off = 1; off < 32; off <<= 1) ssum += __shfl_xor(ssum, off);
        float g = e / ssum;

        if (MODE == 1) {
            Rout[((size_t)b * NN + n) * KK + k] = g;
        } else {
            aN += g;
#pragma unroll
            for (int d = 0; d < DD; d++) {
                aSx[d] = fmaf(g, xv[d], aSx[d]);
                aSxx[d] = fmaf(g * xv[d], xv[d], aSxx[d]);
            }
        }
    }

    if (MODE == 0) {
        __shared__ float red[4][KK * 33];
        aN += __shfl_xor(aN, 32);
#pragma unroll
        for (int d = 0; d < DD; d++) {
            aSx[d] += __shfl_xor(aSx[d], 32);
            aSxx[d] += __shfl_xor(aSxx[d], 32);
        }
        if (jj == 0) {
            red[wave][k * 33 + 0] = aN;
#pragma unroll
            for (int d = 0; d < DD; d++) {
                red[wave][k * 33 + 1 + d] = aSx[d];
                red[wave][k * 33 + 17 + d] = aSxx[d];
            }
        }
        __syncthreads();
        float* outc = accOut + (size_t)(chunk & (ACC_C - 1)) * ACC_STRIDE;
        for (int idx = tid; idx < KK * 33; idx += 256) {
            float v = red[0][idx] + red[1][idx] + red[2][idx] + red[3][idx];
            int kk2 = idx / 33, j = idx % 33;
            float* dst;
            if (j == 0) dst = outc + b * KK + kk2;
            else if (j < 17) dst = outc + 1024 + (size_t)(b * KK + kk2) * DD + (j - 1);
            else dst = outc + 17408 + (size_t)(b * KK + kk2) * DD + (j - 17);
            unsafeAtomicAdd(dst, v);
        }
    }
}

// v7: R7 structure + explicit software pipelining of the LDS x-broadcasts:
// x-row register double-buffer across the b-loop (read x[i+1] while doing
// the 17-fma dot on x[i]); W register double-buffer across j (from R7).
// All arrays statically indexed (rule: runtime-indexed regs -> scratch).
__global__ __launch_bounds__(512, 2) void k_caps(
    const float* __restrict__ x, const float* __restrict__ W,
    const float* __restrict__ R, float* __restrict__ s) {
    __shared__ float xs[4][BN][DD];  // 8 KB
    __shared__ float rs[4][BN][KK];  // 16 KB
    const int tid = threadIdx.x;     // slot = k*16 + d
    const int k = tid >> 4;
    const int n0 = blockIdx.x * 4;
    float* sc = s + (size_t)(blockIdx.x & (SC - 1)) * (BN * KK * DD);

    {   // x: 4n*32b*4 = 512 float4, one per thread
        int j = tid >> 7, b = (tid >> 2) & 31, e4 = tid & 3;
        *(float4*)&xs[j][b][e4 * 4] =
            *(const float4*)(x + ((size_t)b * NN + n0 + j) * DD + e4 * 4);
    }
#pragma unroll
    for (int q = tid; q < 1024; q += 512) {  // R: 1024 float4, two per thread
        int j = q >> 8, b = (q >> 3) & 31, k4 = q & 7;
        *(float4*)&rs[j][b][k4 * 4] =
            *(const float4*)(R + ((size_t)b * NN + n0 + j) * KK + k4 * 4);
    }
    __syncthreads();

#pragma unroll 1
    for (int half = 0; half < 2; half++) {
        const int b0 = half * 16;
        float sacc[16];
#pragma unroll
        for (int i = 0; i < 16; i++) sacc[i] = 0.f;

        const float4* wp0 = (const float4*)(W + ((size_t)n0 * (KK * DD) + tid) * DD);
        float4 wa0 = wp0[0], wa1 = wp0[1], wa2 = wp0[2], wa3 = wp0[3];

#pragma unroll
        for (int j = 0; j < 4; j++) {
            float4 wb0, wb1, wb2, wb3;
            if (j < 3) {
                const float4* wp = (const float4*)(W + ((size_t)(n0 + j + 1) * (KK * DD) + tid) * DD);
                wb0 = wp[0]; wb1 = wp[1]; wb2 = wp[2]; wb3 = wp[3];
            } else {
                wb0 = wa0; wb1 = wa1; wb2 = wa2; wb3 = wa3;
            }
            // prime x pipeline with b0's row
            const float4* xv0 = (const float4*)&xs[j][b0][0];
            float4 xa0 = xv0[0], xa1 = xv0[1], xa2 = xv0[2], xa3 = xv0[3];
#pragma unroll
            for (int i = 0; i < 16; i++) {
                // prefetch next x-row while computing this one
                float4 xn0, xn1, xn2, xn3;
                if (i < 15) {
                    const float4* xv = (const float4*)&xs[j][b0 + i + 1][0];
                    xn0 = xv[0]; xn1 = xv[1]; xn2 = xv[2]; xn3 = xv[3];
                } else {
                    xn0 = xa0; xn1 = xa1; xn2 = xa2; xn3 = xa3;
                }
                float r = rs[j][b0 + i][k];
                float p0 = wa0.x * xa0.x, p1 = wa0.y * xa0.y;
                float p2 = wa0.z * xa0.z, p3 = wa0.w * xa0.w;
                p0 = fmaf(wa1.x, xa1.x, p0); p1 = fmaf(wa1.y, xa1.y, p1);
                p2 = fmaf(wa1.z, xa1.z, p2); p3 = fmaf(wa1.w, xa1.w, p3);
                p0 = fmaf(wa2.x, xa2.x, p0); p1 = fmaf(wa2.y, xa2.y, p1);
                p2 = fmaf(wa2.z, xa2.z, p2); p3 = fmaf(wa2.w, xa2.w, p3);
                p0 = fmaf(wa3.x, xa3.x, p0); p1 = fmaf(wa3.y, xa3.y, p1);
                p2 = fmaf(wa3.z, xa3.z, p2); p3 = fmaf(wa3.w, xa3.w, p3);
                float caps = (p0 + p1) + (p2 + p3);
                sacc[i] = fmaf(r, caps, sacc[i]);
                xa0 = xn0; xa1 = xn1; xa2 = xn2; xa3 = xn3;
            }
            wa0 = wb0; wa1 = wb1; wa2 = wb2; wa3 = wb3;
        }
#pragma unroll
        for (int i = 0; i < 16; i++) {
            unsafeAtomicAdd(sc + (size_t)(b0 + i) * (KK * DD) + tid, sacc[i]);
        }
    }
}

// thread per (b,k,d); sum SC copies coalesced; 16-lane shuffle for the norm.
__global__ void k_squash(const float* __restrict__ s, float* __restrict__ out) {
    int idx = blockIdx.x * 256 + threadIdx.x;  // 16384 = BN*KK*DD
    float v = 0.f;
#pragma unroll 8
    for (int c = 0; c < SC; c++) v += s[(size_t)c * (BN * KK * DD) + idx];
    float ss = v * v;
#pragma unroll
    for (int off = 1; off < 16; off <<= 1) ss += __shfl_xor(ss, off);
    ss += 1e-7f;
    float scale = sqrtf(ss) / (1.0f + ss);
    out[idx] = v * scale;
}

extern "C" void kernel_launch(void* const* d_in, const int* in_sizes, int n_in,
                              void* d_out, int out_size, void* d_ws, size_t ws_size,
                              hipStream_t stream) {
    const float* x   = (const float*)d_in[0];
    const float* W   = (const float*)d_in[1];
    const float* mu0 = (const float*)d_in[2];
    float* ws   = (float*)d_ws;
    float* accA = ws;
    float* accB = ws + 135168;
    float* s    = ws + 270336;
    float* R    = ws + 1318912;

    hipMemsetAsync(ws, 0, (size_t)1318912 * sizeof(float), stream);

    // iteration 1 (mu = mu0, sigma = 1, pi = 1/32) -> accA
    k_estep<0, 1><<<1024, 256, 0, stream>>>(x, mu0, nullptr, accA, nullptr);
    // iteration 2: finalize from accA inline -> accB
    k_estep<0, 0><<<1024, 256, 0, stream>>>(x, nullptr, accA, accB, nullptr);
    // iteration 3: finalize from accB inline -> R only
    k_estep<1, 0><<<1024, 256, 0, stream>>>(x, nullptr, accB, nullptr, R);

    k_caps<<<512, 512, 0, stream>>>(x, W, R, s);
    k_squash<<<64, 256, 0, stream>>>(s, (float*)d_out);
}

// Round 9
// 101.677 us; speedup vs baseline: 1.3878x; 1.0625x over previous
//
#include <hip/hip_runtime.h>
#include <hip/hip_bf16.h>
#include <math.h>

#define BN 32
#define NN 2048
#define KK 32
#define DD 16
#define SC 32        // split copies of s (atomic chain = 256/32 = 8)
#define ACC_C 4      // split copies of estep accumulators
#define ACC_STRIDE 33792  // per-copy: N[1024] + Sx[16384] + Sxx[16384]

// ws layout (floats):
// 0        : accA   [135168]
// 135168   : accB   [135168]      (zero block: 0..794624)
// 270336   : s      [SC*16384 = 524288]
// 794624   : R3     [2097152]     (fragment-ordered R, fully overwritten)
// 2891776  : xpk    [524288]      (x bf16 A-fragments, 1M ushorts)
// total 3416064 floats = 13.7 MB

typedef __attribute__((ext_vector_type(8))) short bf16x8;
typedef __attribute__((ext_vector_type(16))) float f32x16;

static __device__ __forceinline__ ushort f2bf(float f) {
    unsigned int u = __float_as_uint(f);
    return (ushort)((u + 0x7FFFu + ((u >> 16) & 1u)) >> 16);  // RNE
}

// MODE 0: accumulate N, Sx, Sxx into accOut. MODE 1: write R3 (fragment order).
// FIRST 1: params from mu0 (sigma=1, pi=1/32); else inline-finalize from accIn.
template <int MODE, int FIRST>
__global__ __launch_bounds__(256, 4) void k_estep(
    const float* __restrict__ x, const float* __restrict__ mu0,
    const float* __restrict__ accIn, float* __restrict__ accOut,
    float* __restrict__ R3) {
    const int b = blockIdx.x >> 5;      // 32 b
    const int chunk = blockIdx.x & 31;  // 32 chunks of 64 n
    const int tid = threadIdx.x;
    const int wave = tid >> 6;
    const int lane = tid & 63;
    const int k = lane & 31;
    const int jj = lane >> 5;

    float mk[DD], ik[DD], ck;
    if (FIRST) {
        const float4* mp = (const float4*)(mu0 + (size_t)(b * KK + k) * DD);
#pragma unroll
        for (int q = 0; q < 4; q++) {
            float4 m4 = mp[q];
            mk[q*4+0]=m4.x; mk[q*4+1]=m4.y; mk[q*4+2]=m4.z; mk[q*4+3]=m4.w;
        }
#pragma unroll
        for (int d = 0; d < DD; d++) ik[d] = 1.0f;
        ck = -3.4657359028f;  // log(1/32)
    } else {
        float N = 0.f, sxv[DD], sxxv[DD];
#pragma unroll
        for (int d = 0; d < DD; d++) { sxv[d] = 0.f; sxxv[d] = 0.f; }
#pragma unroll
        for (int c = 0; c < ACC_C; c++) {
            const float* base = accIn + (size_t)c * ACC_STRIDE;
            N += base[b * KK + k];
            const float4* sxp  = (const float4*)(base + 1024  + (size_t)(b * KK + k) * DD);
            const float4* sxxp = (const float4*)(base + 17408 + (size_t)(b * KK + k) * DD);
#pragma unroll
            for (int q = 0; q < 4; q++) {
                float4 a = sxp[q], c2 = sxxp[q];
                sxv[q*4+0]+=a.x; sxv[q*4+1]+=a.y; sxv[q*4+2]+=a.z; sxv[q*4+3]+=a.w;
                sxxv[q*4+0]+=c2.x; sxxv[q*4+1]+=c2.y; sxxv[q*4+2]+=c2.z; sxxv[q*4+3]+=c2.w;
            }
        }
        float invN = 1.0f / N;
        float sumlog = 0.f;
#pragma unroll
        for (int d = 0; d < DD; d++) {
            float m_ = sxv[d] * invN;
            float v = fmaxf(sxxv[d] * invN - m_ * m_, 1e-12f);
            mk[d] = m_;
            ik[d] = rsqrtf(v);
            sumlog += __logf(v);
        }
        ck = __logf(N * (1.0f / NN)) - 0.5f * sumlog;
    }

    float aN = 0.f, aSx[DD], aSxx[DD];
#pragma unroll
    for (int d = 0; d < DD; d++) { aSx[d] = 0.f; aSxx[d] = 0.f; }

    // fragment-order coords for R3 writes (b is block-uniform)
    const int hi_b = (b >> 2) & 1;
    const int pos_b = (b & 3) | (((b >> 3) & 3) << 2);

#pragma unroll 4
    for (int i = 0; i < 8; i++) {
        const int n = chunk * 64 + i * 8 + wave * 2 + jj;
        const float4* xp = (const float4*)(x + ((size_t)b * NN + n) * DD);
        float xv[DD];
#pragma unroll
        for (int q = 0; q < 4; q++) {
            float4 v = xp[q];
            xv[q*4+0]=v.x; xv[q*4+1]=v.y; xv[q*4+2]=v.z; xv[q*4+3]=v.w;
        }
        float qd = 0.f;
#pragma unroll
        for (int d = 0; d < DD; d++) {
            float z = (xv[d] - mk[d]) * ik[d];
            qd = fmaf(z, z, qd);
        }
        float logit = ck - 0.5f * qd;
        float m = logit;
#pragma unroll
        for (int off = 1; off < 32; off <<= 1) m = fmaxf(m, __shfl_xor(m, off));
        float e = __expf(logit - m);
        float ssum = e;
#pragma unroll
        for (int off = 1; off < 32; off <<= 1) ssum += __shfl_xor(ssum, off);
        float g = e / ssum;

        if (MODE == 1) {
            // R3[n][k][hi][pos]
            R3[(((size_t)n * KK + k) * 2 + hi_b) * 16 + pos_b] = g;
        } else {
            aN += g;
#pragma unroll
            for (int d = 0; d < DD; d++) {
                aSx[d] = fmaf(g, xv[d], aSx[d]);
                aSxx[d] = fmaf(g * xv[d], xv[d], aSxx[d]);
            }
        }
    }

    if (MODE == 0) {
        __shared__ float red[4][KK * 33];
        aN += __shfl_xor(aN, 32);
#pragma unroll
        for (int d = 0; d < DD; d++) {
            aSx[d] += __shfl_xor(aSx[d], 32);
            aSxx[d] += __shfl_xor(aSxx[d], 32);
        }
        if (jj == 0) {
            red[wave][k * 33 + 0] = aN;
#pragma unroll
            for (int d = 0; d < DD; d++) {
                red[wave][k * 33 + 1 + d] = aSx[d];
                red[wave][k * 33 + 17 + d] = aSxx[d];
            }
        }
        __syncthreads();
        float* outc = accOut + (size_t)(chunk & (ACC_C - 1)) * ACC_STRIDE;
        for (int idx = tid; idx < KK * 33; idx += 256) {
            float v = red[0][idx] + red[1][idx] + red[2][idx] + red[3][idx];
            int kk2 = idx / 33, j = idx % 33;
            float* dst;
            if (j == 0) dst = outc + b * KK + kk2;
            else if (j < 17) dst = outc + 1024 + (size_t)(b * KK + kk2) * DD + (j - 1);
            else dst = outc + 17408 + (size_t)(b * KK + kk2) * DD + (j - 17);
            unsafeAtomicAdd(dst, v);
        }
    }
}

// pack x into bf16 A-fragments: xpk[n][lane][8] with lane l -> (b=l&31, e=8*(l>>5)..)
__global__ __launch_bounds__(256) void k_xpack(const float* __restrict__ x,
                                               ushort* __restrict__ xpk) {
    int idx = blockIdx.x * 256 + threadIdx.x;   // n*64 + l, total 131072
    int n = idx >> 6, l = idx & 63;
    int b = l & 31, e0 = (l >> 5) * 8;
    const float4* xp = (const float4*)(x + ((size_t)b * NN + n) * DD + e0);
    float4 a = xp[0], c = xp[1];
    ushort* o = xpk + (size_t)idx * 8;
    o[0]=f2bf(a.x); o[1]=f2bf(a.y); o[2]=f2bf(a.z); o[3]=f2bf(a.w);
    o[4]=f2bf(c.x); o[5]=f2bf(c.y); o[6]=f2bf(c.z); o[7]=f2bf(c.w);
}

// v8 (MFMA): per (wave, n): D[32b x 32kd] = mfma_32x32x16_bf16(x-frag, W-frag),
// then sacc[q] += r3[q] * D[q] (per-n R scaling in VALU). No LDS at all.
// blockIdx = chunk*4 + tg; wave w -> t = tg*4+w (kd-tile of 32); chunk = 8 n's.
__global__ __launch_bounds__(256, 4) void k_caps(
    const float* __restrict__ W, const ushort* __restrict__ xpk,
    const float* __restrict__ R3, float* __restrict__ s) {
    const int tid = threadIdx.x;
    const int wv = tid >> 6, l = tid & 63;
    const int chunk = blockIdx.x >> 2, tg = blockIdx.x & 3;
    const int t = tg * 4 + wv;          // kd-tile 0..15
    const int col = l & 31, hi = l >> 5;
    const int kq = (l >> 4) & 1;        // k = 2t + kq
    float* sc = s + (size_t)(chunk & (SC - 1)) * (BN * KK * DD);

    float sacc[16];
#pragma unroll
    for (int q = 0; q < 16; q++) sacc[q] = 0.f;
    const f32x16 zacc = {0.f,0.f,0.f,0.f, 0.f,0.f,0.f,0.f,
                         0.f,0.f,0.f,0.f, 0.f,0.f,0.f,0.f};

#pragma unroll 2
    for (int i = 0; i < 8; i++) {
        const int n = chunk * 8 + i;
        // A-fragment: x, pre-packed bf16, 16B per lane, coalesced
        bf16x8 af = *(const bf16x8*)(xpk + ((size_t)n * 64 + l) * 8);
        // B-fragment: W[n, kd=32t+col, e=8*hi..+7], cvt fp32->bf16 in-regs
        const float4* wp = (const float4*)(W + (((size_t)n * 512 + t * 32 + col) * DD) + hi * 8);
        float4 wlo = wp[0], whi = wp[1];
        bf16x8 bfr;
        bfr[0]=(short)f2bf(wlo.x); bfr[1]=(short)f2bf(wlo.y);
        bfr[2]=(short)f2bf(wlo.z); bfr[3]=(short)f2bf(wlo.w);
        bfr[4]=(short)f2bf(whi.x); bfr[5]=(short)f2bf(whi.y);
        bfr[6]=(short)f2bf(whi.z); bfr[7]=(short)f2bf(whi.w);
        // r values in D-register order: R3[n][2t+kq][hi][0..15]
        const float4* rp = (const float4*)(R3 + (((size_t)n * KK + 2 * t + kq) * 2 + hi) * 16);
        float4 r0 = rp[0], r1 = rp[1], r2 = rp[2], r3v = rp[3];

        f32x16 D = __builtin_amdgcn_mfma_f32_32x32x16_bf16(af, bfr, zacc, 0, 0, 0);

        sacc[0]  = fmaf(r0.x,  D[0],  sacc[0]);
        sacc[1]  = fmaf(r0.y,  D[1],  sacc[1]);
        sacc[2]  = fmaf(r0.z,  D[2],  sacc[2]);
        sacc[3]  = fmaf(r0.w,  D[3],  sacc[3]);
        sacc[4]  = fmaf(r1.x,  D[4],  sacc[4]);
        sacc[5]  = fmaf(r1.y,  D[5],  sacc[5]);
        sacc[6]  = fmaf(r1.z,  D[6],  sacc[6]);
        sacc[7]  = fmaf(r1.w,  D[7],  sacc[7]);
        sacc[8]  = fmaf(r2.x,  D[8],  sacc[8]);
        sacc[9]  = fmaf(r2.y,  D[9],  sacc[9]);
        sacc[10] = fmaf(r2.z,  D[10], sacc[10]);
        sacc[11] = fmaf(r2.w,  D[11], sacc[11]);
        sacc[12] = fmaf(r3v.x, D[12], sacc[12]);
        sacc[13] = fmaf(r3v.y, D[13], sacc[13]);
        sacc[14] = fmaf(r3v.z, D[14], sacc[14]);
        sacc[15] = fmaf(r3v.w, D[15], sacc[15]);
    }

    const int kd = t * 32 + col;
#pragma unroll
    for (int q = 0; q < 16; q++) {
        const int b = (q & 3) + 8 * (q >> 2) + 4 * hi;  // verified C/D row map
        unsafeAtomicAdd(sc + (size_t)b * (KK * DD) + kd, sacc[q]);
    }
}

// thread per (b,k,d); sum SC copies coalesced; 16-lane shuffle for the norm.
__global__ void k_squash(const float* __restrict__ s, float* __restrict__ out) {
    int idx = blockIdx.x * 256 + threadIdx.x;  // 16384 = BN*KK*DD
    float v = 0.f;
#pragma unroll 8
    for (int c = 0; c < SC; c++) v += s[(size_t)c * (BN * KK * DD) + idx];
    float ss = v * v;
#pragma unroll
    for (int off = 1; off < 16; off <<= 1) ss += __shfl_xor(ss, off);
    ss += 1e-7f;
    float scale = sqrtf(ss) / (1.0f + ss);
    out[idx] = v * scale;
}

extern "C" void kernel_launch(void* const* d_in, const int* in_sizes, int n_in,
                              void* d_out, int out_size, void* d_ws, size_t ws_size,
                              hipStream_t stream) {
    const float* x   = (const float*)d_in[0];
    const float* W   = (const float*)d_in[1];
    const float* mu0 = (const float*)d_in[2];
    float* ws   = (float*)d_ws;
    float* accA = ws;
    float* accB = ws + 135168;
    float* s    = ws + 270336;
    float* R3   = ws + 794624;
    ushort* xpk = (ushort*)(ws + 2891776);

    hipMemsetAsync(ws, 0, (size_t)794624 * sizeof(float), stream);

    k_xpack<<<512, 256, 0, stream>>>(x, xpk);

    // iteration 1 (mu = mu0, sigma = 1, pi = 1/32) -> accA
    k_estep<0, 1><<<1024, 256, 0, stream>>>(x, mu0, nullptr, accA, nullptr);
    // iteration 2: finalize from accA inline -> accB
    k_estep<0, 0><<<1024, 256, 0, stream>>>(x, nullptr, accA, accB, nullptr);
    // iteration 3: finalize from accB inline -> R3 (fragment order)
    k_estep<1, 0><<<1024, 256, 0, stream>>>(x, nullptr, accB, nullptr, R3);

    k_caps<<<1024, 256, 0, stream>>>(W, xpk, R3, s);
    k_squash<<<64, 256, 0, stream>>>(s, (float*)d_out);
}

// Round 10
// 96.789 us; speedup vs baseline: 1.4579x; 1.0505x over previous
//
#include <hip/hip_runtime.h>
#include <hip/hip_bf16.h>
#include <math.h>

#define BN 32
#define NN 2048
#define KK 32
#define DD 16
#define SC 32        // split copies of s (atomic chain = 256/32 = 8)
#define ACC_C 4      // split copies of estep accumulators
#define ACC_STRIDE 33792  // per-copy: N[1024] + Sx[16384] + Sxx[16384]

// ws layout (floats):
// 0        : accA   [135168]
// 135168   : accB   [135168]      (zero block: 0..794624)
// 270336   : s      [SC*16384 = 524288]
// 794624   : R      [BN*NN*KK = 2097152]   (normal order [b][n][k], fully written)
// 2891776  : xpk    [524288]      (x bf16 A-fragments, 1M ushorts)

typedef __attribute__((ext_vector_type(8))) short bf16x8;
typedef __attribute__((ext_vector_type(16))) float f32x16;

static __device__ __forceinline__ ushort f2bf(float f) {
    unsigned int u = __float_as_uint(f);
    return (ushort)((u + 0x7FFFu + ((u >> 16) & 1u)) >> 16);  // RNE
}

// zero the atomic-accumulator region (in-graph hipMemsetAsync costs ~39us fixed;
// a plain kernel does 3.2 MB in ~1us).  776*256 threads * float4 = 198656*16B.
__global__ void k_zero(float4* __restrict__ p) {
    int i = blockIdx.x * 256 + threadIdx.x;
    p[i] = make_float4(0.f, 0.f, 0.f, 0.f);
}

// MODE 0: accumulate N, Sx, Sxx into accOut. MODE 1: write R (coalesced [b][n][k]).
// FIRST 1: params from mu0 (sigma=1, pi=1/32); else inline-finalize from accIn.
template <int MODE, int FIRST>
__global__ __launch_bounds__(256, 4) void k_estep(
    const float* __restrict__ x, const float* __restrict__ mu0,
    const float* __restrict__ accIn, float* __restrict__ accOut,
    float* __restrict__ Rout) {
    const int b = blockIdx.x >> 5;      // 32 b
    const int chunk = blockIdx.x & 31;  // 32 chunks of 64 n
    const int tid = threadIdx.x;
    const int wave = tid >> 6;
    const int lane = tid & 63;
    const int k = lane & 31;
    const int jj = lane >> 5;

    float mk[DD], ik[DD], ck;
    if (FIRST) {
        const float4* mp = (const float4*)(mu0 + (size_t)(b * KK + k) * DD);
#pragma unroll
        for (int q = 0; q < 4; q++) {
            float4 m4 = mp[q];
            mk[q*4+0]=m4.x; mk[q*4+1]=m4.y; mk[q*4+2]=m4.z; mk[q*4+3]=m4.w;
        }
#pragma unroll
        for (int d = 0; d < DD; d++) ik[d] = 1.0f;
        ck = -3.4657359028f;  // log(1/32)
    } else {
        float N = 0.f, sxv[DD], sxxv[DD];
#pragma unroll
        for (int d = 0; d < DD; d++) { sxv[d] = 0.f; sxxv[d] = 0.f; }
#pragma unroll
        for (int c = 0; c < ACC_C; c++) {
            const float* base = accIn + (size_t)c * ACC_STRIDE;
            N += base[b * KK + k];
            const float4* sxp  = (const float4*)(base + 1024  + (size_t)(b * KK + k) * DD);
            const float4* sxxp = (const float4*)(base + 17408 + (size_t)(b * KK + k) * DD);
#pragma unroll
            for (int q = 0; q < 4; q++) {
                float4 a = sxp[q], c2 = sxxp[q];
                sxv[q*4+0]+=a.x; sxv[q*4+1]+=a.y; sxv[q*4+2]+=a.z; sxv[q*4+3]+=a.w;
                sxxv[q*4+0]+=c2.x; sxxv[q*4+1]+=c2.y; sxxv[q*4+2]+=c2.z; sxxv[q*4+3]+=c2.w;
            }
        }
        float invN = 1.0f / N;
        float sumlog = 0.f;
#pragma unroll
        for (int d = 0; d < DD; d++) {
            float m_ = sxv[d] * invN;
            float v = fmaxf(sxxv[d] * invN - m_ * m_, 1e-12f);
            mk[d] = m_;
            ik[d] = rsqrtf(v);
            sumlog += __logf(v);
        }
        ck = __logf(N * (1.0f / NN)) - 0.5f * sumlog;
    }

    float aN = 0.f, aSx[DD], aSxx[DD];
#pragma unroll
    for (int d = 0; d < DD; d++) { aSx[d] = 0.f; aSxx[d] = 0.f; }

#pragma unroll 4
    for (int i = 0; i < 8; i++) {
        const int n = chunk * 64 + i * 8 + wave * 2 + jj;
        const float4* xp = (const float4*)(x + ((size_t)b * NN + n) * DD);
        float xv[DD];
#pragma unroll
        for (int q = 0; q < 4; q++) {
            float4 v = xp[q];
            xv[q*4+0]=v.x; xv[q*4+1]=v.y; xv[q*4+2]=v.z; xv[q*4+3]=v.w;
        }
        float qd = 0.f;
#pragma unroll
        for (int d = 0; d < DD; d++) {
            float z = (xv[d] - mk[d]) * ik[d];
            qd = fmaf(z, z, qd);
        }
        float logit = ck - 0.5f * qd;
        float m = logit;
#pragma unroll
        for (int off = 1; off < 32; off <<= 1) m = fmaxf(m, __shfl_xor(m, off));
        float e = __expf(logit - m);
        float ssum = e;
#pragma unroll
        for (int off = 1; off < 32; off <<= 1) ssum += __shfl_xor(ssum, off);
        float g = e / ssum;

        if (MODE == 1) {
            Rout[((size_t)b * NN + n) * KK + k] = g;  // coalesced per half-wave
        } else {
            aN += g;
#pragma unroll
            for (int d = 0; d < DD; d++) {
                aSx[d] = fmaf(g, xv[d], aSx[d]);
                aSxx[d] = fmaf(g * xv[d], xv[d], aSxx[d]);
            }
        }
    }

    if (MODE == 0) {
        __shared__ float red[4][KK * 33];
        aN += __shfl_xor(aN, 32);
#pragma unroll
        for (int d = 0; d < DD; d++) {
            aSx[d] += __shfl_xor(aSx[d], 32);
            aSxx[d] += __shfl_xor(aSxx[d], 32);
        }
        if (jj == 0) {
            red[wave][k * 33 + 0] = aN;
#pragma unroll
            for (int d = 0; d < DD; d++) {
                red[wave][k * 33 + 1 + d] = aSx[d];
                red[wave][k * 33 + 17 + d] = aSxx[d];
            }
        }
        __syncthreads();
        float* outc = accOut + (size_t)(chunk & (ACC_C - 1)) * ACC_STRIDE;
        for (int idx = tid; idx < KK * 33; idx += 256) {
            float v = red[0][idx] + red[1][idx] + red[2][idx] + red[3][idx];
            int kk2 = idx / 33, j = idx % 33;
            float* dst;
            if (j == 0) dst = outc + b * KK + kk2;
            else if (j < 17) dst = outc + 1024 + (size_t)(b * KK + kk2) * DD + (j - 1);
            else dst = outc + 17408 + (size_t)(b * KK + kk2) * DD + (j - 17);
            unsafeAtomicAdd(dst, v);
        }
    }
}

// pack x into bf16 A-fragments: xpk[n][lane][8] with lane l -> (b=l&31, e=8*(l>>5)..)
__global__ __launch_bounds__(256) void k_xpack(const float* __restrict__ x,
                                               ushort* __restrict__ xpk) {
    int idx = blockIdx.x * 256 + threadIdx.x;   // n*64 + l, total 131072
    int n = idx >> 6, l = idx & 63;
    int b = l & 31, e0 = (l >> 5) * 8;
    const float4* xp = (const float4*)(x + ((size_t)b * NN + n) * DD + e0);
    float4 a = xp[0], c = xp[1];
    ushort* o = xpk + (size_t)idx * 8;
    o[0]=f2bf(a.x); o[1]=f2bf(a.y); o[2]=f2bf(a.z); o[3]=f2bf(a.w);
    o[4]=f2bf(c.x); o[5]=f2bf(c.y); o[6]=f2bf(c.z); o[7]=f2bf(c.w);
}

// v9 (MFMA): per (wave, n): D[32b x 32kd] = mfma_32x32x16_bf16(x-frag, W-frag),
// then sacc[q] += r(q) * D[q].  r read directly from R[b][n][k]: per wave-load
// only 4 distinct dwords (2b x 2k), L1-resident (block R working set = 4KB/n).
__global__ __launch_bounds__(256, 4) void k_caps(
    const float* __restrict__ W, const ushort* __restrict__ xpk,
    const float* __restrict__ R, float* __restrict__ s) {
    const int tid = threadIdx.x;
    const int wv = tid >> 6, l = tid & 63;
    const int chunk = blockIdx.x >> 2, tg = blockIdx.x & 3;
    const int t = tg * 4 + wv;          // kd-tile 0..15
    const int col = l & 31, hi = l >> 5;
    const int kq = (l >> 4) & 1;        // k = 2t + kq
    float* sc = s + (size_t)(chunk & (SC - 1)) * (BN * KK * DD);

    float sacc[16];
#pragma unroll
    for (int q = 0; q < 16; q++) sacc[q] = 0.f;
    const f32x16 zacc = {0.f,0.f,0.f,0.f, 0.f,0.f,0.f,0.f,
                         0.f,0.f,0.f,0.f, 0.f,0.f,0.f,0.f};

#pragma unroll 2
    for (int i = 0; i < 8; i++) {
        const int n = chunk * 8 + i;
        // A-fragment: x, pre-packed bf16, 16B per lane, coalesced
        bf16x8 af = *(const bf16x8*)(xpk + ((size_t)n * 64 + l) * 8);
        // B-fragment: W[n, kd=32t+col, e=8*hi..+7], cvt fp32->bf16 in-regs
        const float4* wp = (const float4*)(W + (((size_t)n * 512 + t * 32 + col) * DD) + hi * 8);
        float4 wlo = wp[0], whi = wp[1];
        bf16x8 bfr;
        bfr[0]=(short)f2bf(wlo.x); bfr[1]=(short)f2bf(wlo.y);
        bfr[2]=(short)f2bf(wlo.z); bfr[3]=(short)f2bf(wlo.w);
        bfr[4]=(short)f2bf(whi.x); bfr[5]=(short)f2bf(whi.y);
        bfr[6]=(short)f2bf(whi.z); bfr[7]=(short)f2bf(whi.w);
        // r values: R[b(q,hi)][n][2t+kq], b(q,hi) = (q&3) + 8*(q>>2) + 4*hi
        const float* rn = R + (size_t)(4 * hi) * (NN * KK) + (size_t)n * KK + 2 * t + kq;
        float r0  = rn[(size_t) 0 * (NN * KK)];
        float r1  = rn[(size_t) 1 * (NN * KK)];
        float r2  = rn[(size_t) 2 * (NN * KK)];
        float r3  = rn[(size_t) 3 * (NN * KK)];
        float r4  = rn[(size_t) 8 * (NN * KK)];
        float r5  = rn[(size_t) 9 * (NN * KK)];
        float r6  = rn[(size_t)10 * (NN * KK)];
        float r7  = rn[(size_t)11 * (NN * KK)];
        float r8  = rn[(size_t)16 * (NN * KK)];
        float r9  = rn[(size_t)17 * (NN * KK)];
        float r10 = rn[(size_t)18 * (NN * KK)];
        float r11 = rn[(size_t)19 * (NN * KK)];
        float r12 = rn[(size_t)24 * (NN * KK)];
        float r13 = rn[(size_t)25 * (NN * KK)];
        float r14 = rn[(size_t)26 * (NN * KK)];
        float r15 = rn[(size_t)27 * (NN * KK)];

        f32x16 D = __builtin_amdgcn_mfma_f32_32x32x16_bf16(af, bfr, zacc, 0, 0, 0);

        sacc[0]  = fmaf(r0,  D[0],  sacc[0]);
        sacc[1]  = fmaf(r1,  D[1],  sacc[1]);
        sacc[2]  = fmaf(r2,  D[2],  sacc[2]);
        sacc[3]  = fmaf(r3,  D[3],  sacc[3]);
        sacc[4]  = fmaf(r4,  D[4],  sacc[4]);
        sacc[5]  = fmaf(r5,  D[5],  sacc[5]);
        sacc[6]  = fmaf(r6,  D[6],  sacc[6]);
        sacc[7]  = fmaf(r7,  D[7],  sacc[7]);
        sacc[8]  = fmaf(r8,  D[8],  sacc[8]);
        sacc[9]  = fmaf(r9,  D[9],  sacc[9]);
        sacc[10] = fmaf(r10, D[10], sacc[10]);
        sacc[11] = fmaf(r11, D[11], sacc[11]);
        sacc[12] = fmaf(r12, D[12], sacc[12]);
        sacc[13] = fmaf(r13, D[13], sacc[13]);
        sacc[14] = fmaf(r14, D[14], sacc[14]);
        sacc[15] = fmaf(r15, D[15], sacc[15]);
    }

    const int kd = t * 32 + col;
#pragma unroll
    for (int q = 0; q < 16; q++) {
        const int b = (q & 3) + 8 * (q >> 2) + 4 * hi;  // verified C/D row map
        unsafeAtomicAdd(sc + (size_t)b * (KK * DD) + kd, sacc[q]);
    }
}

// thread per (b,k,d); sum SC copies coalesced; 16-lane shuffle for the norm.
__global__ void k_squash(const float* __restrict__ s, float* __restrict__ out) {
    int idx = blockIdx.x * 256 + threadIdx.x;  // 16384 = BN*KK*DD
    float v = 0.f;
#pragma unroll 8
    for (int c = 0; c < SC; c++) v += s[(size_t)c * (BN * KK * DD) + idx];
    float ss = v * v;
#pragma unroll
    for (int off = 1; off < 16; off <<= 1) ss += __shfl_xor(ss, off);
    ss += 1e-7f;
    float scale = sqrtf(ss) / (1.0f + ss);
    out[idx] = v * scale;
}

extern "C" void kernel_launch(void* const* d_in, const int* in_sizes, int n_in,
                              void* d_out, int out_size, void* d_ws, size_t ws_size,
                              hipStream_t stream) {
    const float* x   = (const float*)d_in[0];
    const float* W   = (const float*)d_in[1];
    const float* mu0 = (const float*)d_in[2];
    float* ws   = (float*)d_ws;
    float* accA = ws;
    float* accB = ws + 135168;
    float* s    = ws + 270336;
    float* R    = ws + 794624;
    ushort* xpk = (ushort*)(ws + 2891776);

    k_zero<<<776, 256, 0, stream>>>((float4*)ws);  // accA+accB+s = 794624 floats

    k_xpack<<<512, 256, 0, stream>>>(x, xpk);

    // iteration 1 (mu = mu0, sigma = 1, pi = 1/32) -> accA
    k_estep<0, 1><<<1024, 256, 0, stream>>>(x, mu0, nullptr, accA, nullptr);
    // iteration 2: finalize from accA inline -> accB
    k_estep<0, 0><<<1024, 256, 0, stream>>>(x, nullptr, accA, accB, nullptr);
    // iteration 3: finalize from accB inline -> R (coalesced normal order)
    k_estep<1, 0><<<1024, 256, 0, stream>>>(x, nullptr, accB, nullptr, R);

    k_caps<<<1024, 256, 0, stream>>>(W, xpk, R, s);
    k_squash<<<64, 256, 0, stream>>>(s, (float*)d_out);
}